// Round 7
// baseline (483.206 us; speedup 1.0000x reference)
//
#include <hip/hip_runtime.h>
#include <hip/hip_bf16.h>

typedef __attribute__((ext_vector_type(8))) short short8;
typedef __attribute__((ext_vector_type(4))) float f32x4;

#define B_    8
#define N_    4097
#define C_    768
#define M_TOT (B_*N_)      /* 32776 */
#define K3    (3*C_)       /* 2304  */
#define CHUNKS 16
#define NSTEP 24           /* 768/32 K-steps */

__device__ __forceinline__ float bf2f(unsigned short u) {
  union { unsigned int i; float f; } x; x.i = ((unsigned int)u) << 16; return x.f;
}
__device__ __forceinline__ unsigned short f2bf(float f) {
  union { float f; unsigned int i; } x; x.f = f;
  unsigned int i = x.i + 0x7fffu + ((x.i >> 16) & 1u);
  return (unsigned short)(i >> 16);
}
__device__ __forceinline__ void gload16(const void* g, void* l) {
  __builtin_amdgcn_global_load_lds(
      (const __attribute__((address_space(1))) void*)g,
      (__attribute__((address_space(3))) void*)l, 16, 0, 0);
}

// ---------------- fp32 -> bf16 convert (x then qkv_w, one kernel) ----------------
__global__ __launch_bounds__(256) void cvt_kernel(const float* __restrict__ inx,
                                                  unsigned short* __restrict__ outx,
                                                  const float* __restrict__ inw,
                                                  unsigned short* __restrict__ outw,
                                                  long n4x, long n4tot) {
  long i = (long)blockIdx.x * blockDim.x + threadIdx.x;
  long stride = (long)gridDim.x * blockDim.x;
  for (; i < n4tot; i += stride) {
    const float4* src; ushort4* dst; long j;
    if (i < n4x) { src = (const float4*)inx; dst = (ushort4*)outx; j = i; }
    else         { src = (const float4*)inw; dst = (ushort4*)outw; j = i - n4x; }
    float4 v = src[j];
    ushort4 o;
    o.x = f2bf(v.x); o.y = f2bf(v.y); o.z = f2bf(v.z); o.w = f2bf(v.w);
    dst[j] = o;
  }
}

// ============ GEMM1: qkv = x @ qkv_w^T  (128x256 tile, 4 waves x (64x128), ring-3) ============
// slot: [0,8K) A(128x32), [8K,24K) B(256x32). 3 slots = 72KB -> 2 blocks/CU.
__global__ __launch_bounds__(256, 2) void gemm_qkv_rope(
    const unsigned short* __restrict__ A,    // [32776,768]
    const unsigned short* __restrict__ Bw,   // [2304,768]
    const float* __restrict__ rope,          // [4096,128]
    const float* __restrict__ qb,
    const float* __restrict__ vb,
    unsigned short* __restrict__ qkv)        // planes [3][32776][768]
{
  __shared__ __align__(16) char L[3*24576];
  const int tid  = threadIdx.x;
  const int wave = tid >> 6, lane = tid & 63;
  const int lr = lane & 15, lk = lane >> 4;
  const int wm = wave >> 1, wn = wave & 1;   // 2m x 2n waves, each 64x128 out

  // bijective XCD swizzle: nwg = 257*9 = 2313, q=289, r=1
  const int o = blockIdx.x;
  const int xcd = o & 7, loc = o >> 3;
  const int tile = (xcd < 1 ? xcd*290 : 290 + (xcd-1)*289) + loc;
  const int m0 = (tile / 9) * 128;
  const int n0 = (tile % 9) * 256;

  // staging: thread t covers row (t>>2), 16B-chunk (t&3); two row-halves per region
  const int srow = tid >> 2, schk = tid & 3;
  const int amA0 = min(m0 + srow,      M_TOT-1);
  const int amA1 = min(m0 + 64 + srow, M_TOT-1);
  const unsigned short* gA0 = A + (long)amA0*768 + schk*8;
  const unsigned short* gA1 = A + (long)amA1*768 + schk*8;
  const unsigned short* gB0 = Bw + (long)(n0 +   0 + srow)*768 + schk*8;
  const unsigned short* gB1 = Bw + (long)(n0 +  64 + srow)*768 + schk*8;
  const unsigned short* gB2 = Bw + (long)(n0 + 128 + srow)*768 + schk*8;
  const unsigned short* gB3 = Bw + (long)(n0 + 192 + srow)*768 + schk*8;
  const int dT = tid*16;

  const int abase = (wm*64 + lr)*64 + lk*16;            // A row-major 64B rows
  const int bbase = 8192 + (wn*128 + lr)*64 + lk*16;    // B row-major 64B rows

  f32x4 acc[4][8];
#pragma unroll
  for (int i = 0; i < 4; ++i)
#pragma unroll
    for (int j = 0; j < 8; ++j) acc[i][j] = (f32x4){0.f,0.f,0.f,0.f};

  auto STAGE = [&](int buf, int kk) {
    char* sb = L + buf*24576;
    gload16(gA0 + kk, sb + dT);
    gload16(gA1 + kk, sb + 4096 + dT);
    gload16(gB0 + kk, sb + 8192 + dT);
    gload16(gB1 + kk, sb + 12288 + dT);
    gload16(gB2 + kk, sb + 16384 + dT);
    gload16(gB3 + kk, sb + 20480 + dT);
  };
  auto COMPUTE = [&](int buf) {
    const char* sb = L + buf*24576;
    short8 bfr[8];
#pragma unroll
    for (int ni = 0; ni < 8; ++ni)
      bfr[ni] = *(const short8*)(sb + bbase + ni*1024);
#pragma unroll
    for (int mi = 0; mi < 4; ++mi) {
      short8 af = *(const short8*)(sb + abase + mi*1024);
#pragma unroll
      for (int ni = 0; ni < 8; ++ni)
        acc[mi][ni] = __builtin_amdgcn_mfma_f32_16x16x32_bf16(af, bfr[ni], acc[mi][ni], 0, 0, 0);
    }
  };

  STAGE(0, 0);
  STAGE(1, 32);
  asm volatile("s_waitcnt vmcnt(6)" ::: "memory");   // slot 0 landed; slot 1 in flight
  __builtin_amdgcn_s_barrier();
  __builtin_amdgcn_sched_barrier(0);

  int cur = 0;
  for (int tt = 0; tt < NSTEP-2; ++tt) {
    int stg = cur + 2; if (stg >= 3) stg -= 3;
    STAGE(stg, (tt+2)*32);
    COMPUTE(cur);
    asm volatile("s_waitcnt vmcnt(6)" ::: "memory"); // slot tt+1 landed; tt+2 in flight
    __builtin_amdgcn_sched_barrier(0);
    __builtin_amdgcn_s_barrier();
    __builtin_amdgcn_sched_barrier(0);
    cur = (cur + 1 == 3) ? 0 : cur + 1;
  }
  COMPUTE(cur);
  asm volatile("s_waitcnt vmcnt(0)" ::: "memory");
  __builtin_amdgcn_sched_barrier(0);
  __builtin_amdgcn_s_barrier();
  __builtin_amdgcn_sched_barrier(0);
  cur = (cur + 1 == 3) ? 0 : cur + 1;
  COMPUTE(cur);

  // ---- epilogue: bias + RoPE + bf16 store to planes ----
  const int which = n0 / 768;
  unsigned short* plane = qkv + (long)which*M_TOT*768;
#pragma unroll
  for (int mi = 0; mi < 4; ++mi) {
#pragma unroll
    for (int ni = 0; ni < 8; ++ni) {
      const int gc = n0 + wn*128 + ni*16 + lr;
      const int within = gc - which*768;
      const int d = within & 63;
      float bias = 0.f;
      if (which == 0) bias = qb[within];
      else if (which == 2) bias = vb[within];
#pragma unroll
      for (int r = 0; r < 4; ++r) {
        const int gm = m0 + wm*64 + mi*16 + lk*4 + r;
        float v = acc[mi][ni][r] + bias;
        float pair = __shfl_xor(v, 1);
        float vo = v;
        if (which < 2) {
          const int ntok = gm % 4097;
          if (ntok > 0 && gm < M_TOT) {
            const float* rp = rope + (long)(ntok - 1)*128 + d;
            const float s = rp[0], c = rp[64];
            const float rot = (d & 1) ? pair : -pair;
            vo = v*c + rot*s;
          }
        }
        if (gm < M_TOT) plane[(long)gm*768 + within] = f2bf(vo);
      }
    }
  }
}

// ---------------- kv partials: kv[b,h] = K^T V over an N-chunk ----------------
__global__ __launch_bounds__(256) void kv_partial_kernel(
    const unsigned short* __restrict__ qkv, float* __restrict__ part)
{
  const int bh = blockIdx.y;
  const int b = bh / 12, h = bh % 12;
  const int chunk = blockIdx.x;
  const int per = (N_ + CHUNKS - 1) / CHUNKS;
  const int nst = chunk * per;
  const int nen = min(nst + per, N_);
  const unsigned short* Kpl = qkv + (long)M_TOT*768 + ((long)b*N_)*768 + h*64;
  const unsigned short* Vpl = qkv + (long)2*M_TOT*768 + ((long)b*N_)*768 + h*64;
  __shared__ unsigned short Kl[32*64];
  __shared__ unsigned short Vl[32*64];
  const int t = threadIdx.x;
  const int ty = t >> 4, tx = t & 15;
  const int lrow = t >> 3, lpc = t & 7;
  float acc[4][4] = {};
  for (int nb = nst; nb < nen; nb += 32) {
    const int cnt = min(32, nen - nb);
    __syncthreads();
    if (lrow < cnt) {
      *(uint4*)(Kl + lrow*64 + lpc*8) = *(const uint4*)(Kpl + (long)(nb + lrow)*768 + lpc*8);
      *(uint4*)(Vl + lrow*64 + lpc*8) = *(const uint4*)(Vpl + (long)(nb + lrow)*768 + lpc*8);
    }
    __syncthreads();
#pragma unroll 2
    for (int i = 0; i < cnt; ++i) {
      const ushort4 ku = *(const ushort4*)(Kl + i*64 + ty*4);
      const ushort4 vu = *(const ushort4*)(Vl + i*64 + tx*4);
      float kf[4] = {bf2f(ku.x), bf2f(ku.y), bf2f(ku.z), bf2f(ku.w)};
      float vf[4] = {bf2f(vu.x), bf2f(vu.y), bf2f(vu.z), bf2f(vu.w)};
#pragma unroll
      for (int a = 0; a < 4; ++a)
#pragma unroll
        for (int e = 0; e < 4; ++e) acc[a][e] += kf[a]*vf[e];
    }
  }
  float* dst = part + ((long)chunk*96 + bh)*4096 + (ty*4)*64 + tx*4;
#pragma unroll
  for (int a = 0; a < 4; ++a)
#pragma unroll
    for (int e = 0; e < 4; ++e) dst[a*64 + e] = acc[a][e];
}

// ---- McombT[b][c][h*64+d] = sum_e kv[b,h,d,e]*pw[c,h*64+e] / (hd*N) ----
__global__ __launch_bounds__(256) void mcomb_kernel(const float* __restrict__ part,
                                                    const float* __restrict__ pw,
                                                    unsigned short* __restrict__ McT) {
  const int blk = blockIdx.x;            // 8*12*2 = 192
  const int cs = blk & 1;
  const int h  = (blk >> 1) % 12;
  const int b  = blk / 24;
  const int bh = b*12 + h;
  __shared__ float kvs[64][65];          // kvs[e][d]
  const int t = threadIdx.x;
  const int d_own = t >> 2;
  const int eg = (t & 3) * 16;

  float4 a0 = {0,0,0,0}, a1 = {0,0,0,0}, a2 = {0,0,0,0}, a3 = {0,0,0,0};
  const float4* p4 = (const float4*)part;
#pragma unroll
  for (int ch = 0; ch < CHUNKS; ++ch) {
    const long base = ((long)ch*96 + bh)*1024 + d_own*16 + (t & 3)*4;
    float4 v0 = p4[base+0], v1 = p4[base+1], v2 = p4[base+2], v3 = p4[base+3];
    a0.x += v0.x; a0.y += v0.y; a0.z += v0.z; a0.w += v0.w;
    a1.x += v1.x; a1.y += v1.y; a1.z += v1.z; a1.w += v1.w;
    a2.x += v2.x; a2.y += v2.y; a2.z += v2.z; a2.w += v2.w;
    a3.x += v3.x; a3.y += v3.y; a3.z += v3.z; a3.w += v3.w;
  }
  kvs[eg+ 0][d_own] = a0.x; kvs[eg+ 1][d_own] = a0.y; kvs[eg+ 2][d_own] = a0.z; kvs[eg+ 3][d_own] = a0.w;
  kvs[eg+ 4][d_own] = a1.x; kvs[eg+ 5][d_own] = a1.y; kvs[eg+ 6][d_own] = a1.z; kvs[eg+ 7][d_own] = a1.w;
  kvs[eg+ 8][d_own] = a2.x; kvs[eg+ 9][d_own] = a2.y; kvs[eg+10][d_own] = a2.z; kvs[eg+11][d_own] = a2.w;
  kvs[eg+12][d_own] = a3.x; kvs[eg+13][d_own] = a3.y; kvs[eg+14][d_own] = a3.z; kvs[eg+15][d_own] = a3.w;
  __syncthreads();

  const int lane = t & 63;
  const int w    = t >> 6;
  float kvcol[64];
#pragma unroll
  for (int e = 0; e < 64; ++e) kvcol[e] = kvs[e][lane];

  const float scale = (float)(1.0/(64.0*4097.0));
  const int cbase = cs*384 + w*96;
  for (int i = 0; i < 96; ++i) {
    const int c = cbase + i;
    const float* pwrow = pw + (long)c*768 + h*64;
    float s = 0.f;
#pragma unroll
    for (int e = 0; e < 64; ++e) s += pwrow[e] * kvcol[e];
    McT[((long)b*768 + c)*768 + h*64 + lane] = f2bf(s * scale);
  }
}

// ============ GEMM2: out[b] = Q[b] @ McT[b]^T + proj_b (128x256, 4 waves, ring-3) ============
__global__ __launch_bounds__(256, 2) void gemm_final(
    const unsigned short* __restrict__ qkv,   // q plane = first M_TOT*768
    const unsigned short* __restrict__ McT,   // [8,768,768] bf16
    const float* __restrict__ pb,
    float* __restrict__ out)
{
  __shared__ __align__(16) char L[3*24576];
  const int tid  = threadIdx.x;
  const int wave = tid >> 6, lane = tid & 63;
  const int lr = lane & 15, lk = lane >> 4;
  const int wm = wave >> 1, wn = wave & 1;

  // XCD swizzle: nwg = 8*33*3 = 792 (one batch per XCD)
  const int o = blockIdx.x;
  const int xcd = o & 7, loc = o >> 3;
  const int b  = xcd;
  const int mt = loc / 3, ct = loc % 3;
  const int m0 = mt * 128;
  const int c0 = ct * 256;

  const int srow = tid >> 2, schk = tid & 3;
  const int amA0 = min(m0 + srow,      N_-1);
  const int amA1 = min(m0 + 64 + srow, N_-1);
  const unsigned short* gA0 = qkv + ((long)b*N_ + amA0)*768 + schk*8;
  const unsigned short* gA1 = qkv + ((long)b*N_ + amA1)*768 + schk*8;
  const unsigned short* Bb  = McT + (long)b*768*768;
  const unsigned short* gB0 = Bb + (long)(c0 +   0 + srow)*768 + schk*8;
  const unsigned short* gB1 = Bb + (long)(c0 +  64 + srow)*768 + schk*8;
  const unsigned short* gB2 = Bb + (long)(c0 + 128 + srow)*768 + schk*8;
  const unsigned short* gB3 = Bb + (long)(c0 + 192 + srow)*768 + schk*8;
  const int dT = tid*16;

  const int abase = (wm*64 + lr)*64 + lk*16;
  const int bbase = 8192 + (wn*128 + lr)*64 + lk*16;

  f32x4 acc[4][8];
#pragma unroll
  for (int i = 0; i < 4; ++i)
#pragma unroll
    for (int j = 0; j < 8; ++j) acc[i][j] = (f32x4){0.f,0.f,0.f,0.f};

  auto STAGE = [&](int buf, int kk) {
    char* sb = L + buf*24576;
    gload16(gA0 + kk, sb + dT);
    gload16(gA1 + kk, sb + 4096 + dT);
    gload16(gB0 + kk, sb + 8192 + dT);
    gload16(gB1 + kk, sb + 12288 + dT);
    gload16(gB2 + kk, sb + 16384 + dT);
    gload16(gB3 + kk, sb + 20480 + dT);
  };
  auto COMPUTE = [&](int buf) {
    const char* sb = L + buf*24576;
    short8 bfr[8];
#pragma unroll
    for (int ni = 0; ni < 8; ++ni)
      bfr[ni] = *(const short8*)(sb + bbase + ni*1024);
#pragma unroll
    for (int mi = 0; mi < 4; ++mi) {
      short8 af = *(const short8*)(sb + abase + mi*1024);
#pragma unroll
      for (int ni = 0; ni < 8; ++ni)
        acc[mi][ni] = __builtin_amdgcn_mfma_f32_16x16x32_bf16(af, bfr[ni], acc[mi][ni], 0, 0, 0);
    }
  };

  STAGE(0, 0);
  STAGE(1, 32);
  asm volatile("s_waitcnt vmcnt(6)" ::: "memory");
  __builtin_amdgcn_s_barrier();
  __builtin_amdgcn_sched_barrier(0);

  int cur = 0;
  for (int tt = 0; tt < NSTEP-2; ++tt) {
    int stg = cur + 2; if (stg >= 3) stg -= 3;
    STAGE(stg, (tt+2)*32);
    COMPUTE(cur);
    asm volatile("s_waitcnt vmcnt(6)" ::: "memory");
    __builtin_amdgcn_sched_barrier(0);
    __builtin_amdgcn_s_barrier();
    __builtin_amdgcn_sched_barrier(0);
    cur = (cur + 1 == 3) ? 0 : cur + 1;
  }
  COMPUTE(cur);
  asm volatile("s_waitcnt vmcnt(0)" ::: "memory");
  __builtin_amdgcn_sched_barrier(0);
  __builtin_amdgcn_s_barrier();
  __builtin_amdgcn_sched_barrier(0);
  cur = (cur + 1 == 3) ? 0 : cur + 1;
  COMPUTE(cur);

#pragma unroll
  for (int mi = 0; mi < 4; ++mi) {
#pragma unroll
    for (int ni = 0; ni < 8; ++ni) {
      const int gc = c0 + wn*128 + ni*16 + lr;
      const float bias = pb[gc];
#pragma unroll
      for (int r = 0; r < 4; ++r) {
        const int tok = m0 + wm*64 + mi*16 + lk*4 + r;
        if (tok < N_)
          out[((long)b*N_ + tok)*768 + gc] = acc[mi][ni][r] + bias;
      }
    }
  }
}

extern "C" void kernel_launch(void* const* d_in, const int* in_sizes, int n_in,
                              void* d_out, int out_size, void* d_ws, size_t ws_size,
                              hipStream_t stream) {
  const float* x      = (const float*)d_in[0];
  const float* rope   = (const float*)d_in[1];
  const float* qkv_w  = (const float*)d_in[2];
  const float* q_bias = (const float*)d_in[3];
  const float* v_bias = (const float*)d_in[4];
  const float* proj_w = (const float*)d_in[5];
  const float* proj_b = (const float*)d_in[6];
  float* out = (float*)d_out;

  char* w0 = (char*)d_ws;
  unsigned short* x_bf  = (unsigned short*)w0;                        // dead after gemm1
  unsigned short* wq_bf = (unsigned short*)(w0 + 50343936);
  unsigned short* qkv   = (unsigned short*)(w0 + 50343936 + 3538944);
  float*          part  = (float*)w0;                                 // aliases x_bf
  unsigned short* McT   = (unsigned short*)(w0 + 25165824 + 1572864);

  const long n4x = (long)M_TOT*768/4;
  const long n4w = (long)K3*768/4;
  cvt_kernel<<<2048, 256, 0, stream>>>(x, x_bf, qkv_w, wq_bf, n4x, n4x + n4w);

  gemm_qkv_rope<<<2313, 256, 0, stream>>>(x_bf, wq_bf, rope, q_bias, v_bias, qkv);

  kv_partial_kernel<<<dim3(CHUNKS, 96), 256, 0, stream>>>(qkv, part);
  mcomb_kernel<<<192, 256, 0, stream>>>(part, proj_w, McT);

  gemm_final<<<792, 256, 0, stream>>>(qkv, McT, proj_b, out);
}

// Round 9
// 438.093 us; speedup vs baseline: 1.1030x; 1.1030x over previous
//
#include <hip/hip_runtime.h>
#include <hip/hip_bf16.h>

typedef __attribute__((ext_vector_type(8))) short short8;
typedef __attribute__((ext_vector_type(4))) float f32x4;

#define B_    8
#define N_    4097
#define C_    768
#define M_TOT (B_*N_)      /* 32776 */
#define K3    (3*C_)       /* 2304  */
#define CHUNKS 16
#define NSTEP 24           /* 768/32 K-steps */

__device__ __forceinline__ float bf2f(unsigned short u) {
  union { unsigned int i; float f; } x; x.i = ((unsigned int)u) << 16; return x.f;
}
__device__ __forceinline__ unsigned short f2bf(float f) {
  union { float f; unsigned int i; } x; x.f = f;
  unsigned int i = x.i + 0x7fffu + ((x.i >> 16) & 1u);
  return (unsigned short)(i >> 16);
}
__device__ __forceinline__ void gload16(const void* g, void* l) {
  __builtin_amdgcn_global_load_lds(
      (const __attribute__((address_space(1))) void*)g,
      (__attribute__((address_space(3))) void*)l, 16, 0, 0);
}

// ---------------- fp32 -> bf16 convert (x then qkv_w, one kernel) ----------------
__global__ __launch_bounds__(256) void cvt_kernel(const float* __restrict__ inx,
                                                  unsigned short* __restrict__ outx,
                                                  const float* __restrict__ inw,
                                                  unsigned short* __restrict__ outw,
                                                  long n4x, long n4tot) {
  long i = (long)blockIdx.x * blockDim.x + threadIdx.x;
  long stride = (long)gridDim.x * blockDim.x;
  for (; i < n4tot; i += stride) {
    const float4* src; ushort4* dst; long j;
    if (i < n4x) { src = (const float4*)inx; dst = (ushort4*)outx; j = i; }
    else         { src = (const float4*)inw; dst = (ushort4*)outw; j = i - n4x; }
    float4 v = src[j];
    ushort4 o;
    o.x = f2bf(v.x); o.y = f2bf(v.y); o.z = f2bf(v.z); o.w = f2bf(v.w);
    dst[j] = o;
  }
}

// ============ GEMM1: qkv = x @ qkv_w^T  (128x256 tile, ring-3 BK=32, R6 schedule) ============
// slot layout: [0,8K) A(128x32), [8K,24K) B(256x32). 3 slots = 72KB -> 2 blocks/CU.
__global__ __launch_bounds__(512, 4) void gemm_qkv_rope(
    const unsigned short* __restrict__ A,    // [32776,768]
    const unsigned short* __restrict__ Bw,   // [2304,768]
    const float* __restrict__ rope,          // [4096,128] sin||cos
    const float* __restrict__ qb,
    const float* __restrict__ vb,
    unsigned short* __restrict__ qkv)        // planes [3][32776][768]
{
  __shared__ __align__(16) char L[3*24576];
  const int tid  = threadIdx.x;
  const int wave = tid >> 6, lane = tid & 63;
  const int lr = lane & 15, lk = lane >> 4;
  const int wm = wave >> 2, wn = wave & 3;   // 2m x 4n waves, each 64x64 out

  // bijective XCD swizzle: nwg = 2313, q=289, r=1; m-fastest within XCD
  const int o = blockIdx.x;
  const int xcd = o & 7, loc = o >> 3;
  const int tile = (xcd < 1 ? xcd*290 : 290 + (xcd-1)*289) + loc;
  const int m0 = (tile % 257) * 128;         // m-fastest: B-panel L2-hot, A via L3
  const int n0 = (tile / 257) * 256;

  const int arow = tid >> 2, achk = tid & 3;
  const int am = min(m0 + arow, M_TOT-1);
  const unsigned short* gA  = A  + (long)am*768 + achk*8;
  const unsigned short* gB1 = Bw + (long)(n0 + arow)*768 + achk*8;
  const unsigned short* gB2 = Bw + (long)(n0 + arow + 128)*768 + achk*8;
  const int dA  = wave*1024;
  const int dB1 = 8192  + wave*1024;
  const int dB2 = 16384 + wave*1024;

  const int abase = (wm*64 + lr)*64 + lk*16;
  const int bbase = 8192 + (wn*64 + lr)*64 + lk*16;

  f32x4 acc[4][4];
#pragma unroll
  for (int i = 0; i < 4; ++i)
#pragma unroll
    for (int j = 0; j < 4; ++j) acc[i][j] = (f32x4){0.f,0.f,0.f,0.f};

  auto STAGE = [&](int buf, int kk) {
    char* sb = L + buf*24576;
    gload16(gA  + kk, sb + dA);
    gload16(gB1 + kk, sb + dB1);
    gload16(gB2 + kk, sb + dB2);
  };
  auto COMPUTE = [&](int buf) {
    const char* sb = L + buf*24576;
    short8 af[4], bfr[4];
#pragma unroll
    for (int mi = 0; mi < 4; ++mi)
      af[mi] = *(const short8*)(sb + abase + mi*1024);
#pragma unroll
    for (int ni = 0; ni < 4; ++ni)
      bfr[ni] = *(const short8*)(sb + bbase + ni*1024);
#pragma unroll
    for (int mi = 0; mi < 4; ++mi)
#pragma unroll
      for (int ni = 0; ni < 4; ++ni)
        acc[mi][ni] = __builtin_amdgcn_mfma_f32_16x16x32_bf16(af[mi], bfr[ni], acc[mi][ni], 0, 0, 0);
  };

  STAGE(0, 0);
  STAGE(1, 32);
  asm volatile("s_waitcnt vmcnt(3)" ::: "memory");
  __builtin_amdgcn_s_barrier();
  __builtin_amdgcn_sched_barrier(0);

  int cur = 0;
  for (int tt = 0; tt < NSTEP-2; ++tt) {
    int stg = cur + 2; if (stg >= 3) stg -= 3;
    STAGE(stg, (tt+2)*32);
    COMPUTE(cur);
    asm volatile("s_waitcnt vmcnt(3)" ::: "memory");
    __builtin_amdgcn_sched_barrier(0);
    __builtin_amdgcn_s_barrier();
    __builtin_amdgcn_sched_barrier(0);
    cur = (cur + 1 == 3) ? 0 : cur + 1;
  }
  COMPUTE(cur);
  asm volatile("s_waitcnt vmcnt(0)" ::: "memory");
  __builtin_amdgcn_sched_barrier(0);
  __builtin_amdgcn_s_barrier();
  __builtin_amdgcn_sched_barrier(0);
  cur = (cur + 1 == 3) ? 0 : cur + 1;
  COMPUTE(cur);

  // ---- epilogue: bias (+RoPE for q/k) + bf16 store to planes ----
  const int which = n0 / 768;                 // block-uniform (768 % 256 == 0)
  unsigned short* plane = qkv + (long)which*M_TOT*768;

  float biasv[4]; int withv[4]; int dv[4];
#pragma unroll
  for (int ni = 0; ni < 4; ++ni) {
    const int gc = n0 + wn*64 + ni*16 + lr;
    const int within = gc - which*768;
    withv[ni] = within;
    dv[ni] = within & 63;
    biasv[ni] = (which == 0) ? qb[within] : (which == 2 ? vb[within] : 0.f);
  }

  if (which == 2) {                           // V: no rope, no shfl, no %
#pragma unroll
    for (int mi = 0; mi < 4; ++mi)
#pragma unroll
      for (int r = 0; r < 4; ++r) {
        const int gm = m0 + wm*64 + mi*16 + lk*4 + r;
        if (gm < M_TOT) {
#pragma unroll
          for (int ni = 0; ni < 4; ++ni)
            plane[(long)gm*768 + withv[ni]] = f2bf(acc[mi][ni][r] + biasv[ni]);
        }
      }
  } else {                                    // Q/K: rope
#pragma unroll
    for (int mi = 0; mi < 4; ++mi) {
#pragma unroll
      for (int r = 0; r < 4; ++r) {
        const int gm = m0 + wm*64 + mi*16 + lk*4 + r;
        const int ntok = gm % 4097;           // once per (mi,r)
        const bool valid = gm < M_TOT;
        const bool dorope = (ntok > 0) && valid;
        const float* rp = rope + (long)(ntok - 1)*128;
#pragma unroll
        for (int ni = 0; ni < 4; ++ni) {
          float v = acc[mi][ni][r] + biasv[ni];
          float pair = __shfl_xor(v, 1);      // col d^1 lives in lane^1
          float vo = v;
          if (dorope) {
            const float s = rp[dv[ni]], c = rp[64 + dv[ni]];
            const float rot = (dv[ni] & 1) ? pair : -pair;
            vo = v*c + rot*s;
          }
          if (valid) plane[(long)gm*768 + withv[ni]] = f2bf(vo);
        }
      }
    }
  }
}

// ---------------- kv partials: kv[b,h] = K^T V over an N-chunk ----------------
__global__ __launch_bounds__(256) void kv_partial_kernel(
    const unsigned short* __restrict__ qkv, float* __restrict__ part)
{
  const int bh = blockIdx.y;
  const int b = bh / 12, h = bh % 12;
  const int chunk = blockIdx.x;
  const int per = (N_ + CHUNKS - 1) / CHUNKS;
  const int nst = chunk * per;
  const int nen = min(nst + per, N_);
  const unsigned short* Kpl = qkv + (long)M_TOT*768 + ((long)b*N_)*768 + h*64;
  const unsigned short* Vpl = qkv + (long)2*M_TOT*768 + ((long)b*N_)*768 + h*64;
  __shared__ unsigned short Kl[32*64];
  __shared__ unsigned short Vl[32*64];
  const int t = threadIdx.x;
  const int ty = t >> 4, tx = t & 15;
  const int lrow = t >> 3, lpc = t & 7;
  float acc[4][4] = {};
  for (int nb = nst; nb < nen; nb += 32) {
    const int cnt = min(32, nen - nb);
    __syncthreads();
    if (lrow < cnt) {
      *(uint4*)(Kl + lrow*64 + lpc*8) = *(const uint4*)(Kpl + (long)(nb + lrow)*768 + lpc*8);
      *(uint4*)(Vl + lrow*64 + lpc*8) = *(const uint4*)(Vpl + (long)(nb + lrow)*768 + lpc*8);
    }
    __syncthreads();
#pragma unroll 2
    for (int i = 0; i < cnt; ++i) {
      const ushort4 ku = *(const ushort4*)(Kl + i*64 + ty*4);
      const ushort4 vu = *(const ushort4*)(Vl + i*64 + tx*4);
      float kf[4] = {bf2f(ku.x), bf2f(ku.y), bf2f(ku.z), bf2f(ku.w)};
      float vf[4] = {bf2f(vu.x), bf2f(vu.y), bf2f(vu.z), bf2f(vu.w)};
#pragma unroll
      for (int a = 0; a < 4; ++a)
#pragma unroll
        for (int e = 0; e < 4; ++e) acc[a][e] += kf[a]*vf[e];
    }
  }
  float* dst = part + ((long)chunk*96 + bh)*4096 + (ty*4)*64 + tx*4;
#pragma unroll
  for (int a = 0; a < 4; ++a)
#pragma unroll
    for (int e = 0; e < 4; ++e) dst[a*64 + e] = acc[a][e];
}

// ---- McombT[b][c][h*64+d] = sum_e kv[b,h,d,e]*pw[c,h*64+e] / (hd*N) ----
__global__ __launch_bounds__(256) void mcomb_kernel(const float* __restrict__ part,
                                                    const float* __restrict__ pw,
                                                    unsigned short* __restrict__ McT) {
  const int blk = blockIdx.x;            // 8*12*2 = 192
  const int cs = blk & 1;
  const int h  = (blk >> 1) % 12;
  const int b  = blk / 24;
  const int bh = b*12 + h;
  __shared__ float kvs[64][65];          // kvs[e][d]
  const int t = threadIdx.x;
  const int d_own = t >> 2;
  const int eg = (t & 3) * 16;

  float4 a0 = {0,0,0,0}, a1 = {0,0,0,0}, a2 = {0,0,0,0}, a3 = {0,0,0,0};
  const float4* p4 = (const float4*)part;
#pragma unroll
  for (int ch = 0; ch < CHUNKS; ++ch) {
    const long base = ((long)ch*96 + bh)*1024 + d_own*16 + (t & 3)*4;
    float4 v0 = p4[base+0], v1 = p4[base+1], v2 = p4[base+2], v3 = p4[base+3];
    a0.x += v0.x; a0.y += v0.y; a0.z += v0.z; a0.w += v0.w;
    a1.x += v1.x; a1.y += v1.y; a1.z += v1.z; a1.w += v1.w;
    a2.x += v2.x; a2.y += v2.y; a2.z += v2.z; a2.w += v2.w;
    a3.x += v3.x; a3.y += v3.y; a3.z += v3.z; a3.w += v3.w;
  }
  kvs[eg+ 0][d_own] = a0.x; kvs[eg+ 1][d_own] = a0.y; kvs[eg+ 2][d_own] = a0.z; kvs[eg+ 3][d_own] = a0.w;
  kvs[eg+ 4][d_own] = a1.x; kvs[eg+ 5][d_own] = a1.y; kvs[eg+ 6][d_own] = a1.z; kvs[eg+ 7][d_own] = a1.w;
  kvs[eg+ 8][d_own] = a2.x; kvs[eg+ 9][d_own] = a2.y; kvs[eg+10][d_own] = a2.z; kvs[eg+11][d_own] = a2.w;
  kvs[eg+12][d_own] = a3.x; kvs[eg+13][d_own] = a3.y; kvs[eg+14][d_own] = a3.z; kvs[eg+15][d_own] = a3.w;
  __syncthreads();

  const int lane = t & 63;
  const int w    = t >> 6;
  float kvcol[64];
#pragma unroll
  for (int e = 0; e < 64; ++e) kvcol[e] = kvs[e][lane];

  const float scale = (float)(1.0/(64.0*4097.0));
  const int cbase = cs*384 + w*96;
  for (int i = 0; i < 96; ++i) {
    const int c = cbase + i;
    const float* pwrow = pw + (long)c*768 + h*64;
    float s = 0.f;
#pragma unroll
    for (int e = 0; e < 64; ++e) s += pwrow[e] * kvcol[e];
    McT[((long)b*768 + c)*768 + h*64 + lane] = f2bf(s * scale);
  }
}

// ============ GEMM2: out[b] = Q[b] @ McT[b]^T + proj_b (128x256 tile, ring-3) ============
__global__ __launch_bounds__(512, 4) void gemm_final(
    const unsigned short* __restrict__ qkv,   // q plane = first M_TOT*768
    const unsigned short* __restrict__ McT,   // [8,768,768] bf16
    const float* __restrict__ pb,
    float* __restrict__ out)
{
  __shared__ __align__(16) char L[3*24576];
  const int tid  = threadIdx.x;
  const int wave = tid >> 6, lane = tid & 63;
  const int lr = lane & 15, lk = lane >> 4;
  const int wm = wave >> 2, wn = wave & 3;

  // XCD swizzle: nwg = 8*33*3 = 792 (one batch per XCD); mt-fastest within XCD
  const int o = blockIdx.x;
  const int xcd = o & 7, loc = o >> 3;
  const int b  = xcd;
  const int ct = loc / 33, mt = loc % 33;    // mt-fastest: McT-slice L2-hot
  const int m0 = mt * 128;
  const int c0 = ct * 256;

  const int arow = tid >> 2, achk = tid & 3;
  const int am = min(m0 + arow, N_-1);
  const unsigned short* gA  = qkv + ((long)b*N_ + am)*768 + achk*8;
  const unsigned short* Bb  = McT + (long)b*768*768;
  const unsigned short* gB1 = Bb + (long)(c0 + arow)*768 + achk*8;
  const unsigned short* gB2 = Bb + (long)(c0 + arow + 128)*768 + achk*8;
  const int dA  = wave*1024;
  const int dB1 = 8192  + wave*1024;
  const int dB2 = 16384 + wave*1024;

  const int abase = (wm*64 + lr)*64 + lk*16;
  const int bbase = 8192 + (wn*64 + lr)*64 + lk*16;

  f32x4 acc[4][4];
#pragma unroll
  for (int i = 0; i < 4; ++i)
#pragma unroll
    for (int j = 0; j < 4; ++j) acc[i][j] = (f32x4){0.f,0.f,0.f,0.f};

  auto STAGE = [&](int buf, int kk) {
    char* sb = L + buf*24576;
    gload16(gA  + kk, sb + dA);
    gload16(gB1 + kk, sb + dB1);
    gload16(gB2 + kk, sb + dB2);
  };
  auto COMPUTE = [&](int buf) {
    const char* sb = L + buf*24576;
    short8 af[4], bfr[4];
#pragma unroll
    for (int mi = 0; mi < 4; ++mi)
      af[mi] = *(const short8*)(sb + abase + mi*1024);
#pragma unroll
    for (int ni = 0; ni < 4; ++ni)
      bfr[ni] = *(const short8*)(sb + bbase + ni*1024);
#pragma unroll
    for (int mi = 0; mi < 4; ++mi)
#pragma unroll
      for (int ni = 0; ni < 4; ++ni)
        acc[mi][ni] = __builtin_amdgcn_mfma_f32_16x16x32_bf16(af[mi], bfr[ni], acc[mi][ni], 0, 0, 0);
  };

  STAGE(0, 0);
  STAGE(1, 32);
  asm volatile("s_waitcnt vmcnt(3)" ::: "memory");
  __builtin_amdgcn_s_barrier();
  __builtin_amdgcn_sched_barrier(0);

  int cur = 0;
  for (int tt = 0; tt < NSTEP-2; ++tt) {
    int stg = cur + 2; if (stg >= 3) stg -= 3;
    STAGE(stg, (tt+2)*32);
    COMPUTE(cur);
    asm volatile("s_waitcnt vmcnt(3)" ::: "memory");
    __builtin_amdgcn_sched_barrier(0);
    __builtin_amdgcn_s_barrier();
    __builtin_amdgcn_sched_barrier(0);
    cur = (cur + 1 == 3) ? 0 : cur + 1;
  }
  COMPUTE(cur);
  asm volatile("s_waitcnt vmcnt(0)" ::: "memory");
  __builtin_amdgcn_sched_barrier(0);
  __builtin_amdgcn_s_barrier();
  __builtin_amdgcn_sched_barrier(0);
  cur = (cur + 1 == 3) ? 0 : cur + 1;
  COMPUTE(cur);

#pragma unroll
  for (int mi = 0; mi < 4; ++mi) {
#pragma unroll
    for (int ni = 0; ni < 4; ++ni) {
      const int gc = c0 + wn*64 + ni*16 + lr;
      const float bias = pb[gc];
#pragma unroll
      for (int r = 0; r < 4; ++r) {
        const int tok = m0 + wm*64 + mi*16 + lk*4 + r;
        if (tok < N_)
          out[((long)b*N_ + tok)*768 + gc] = acc[mi][ni][r] + bias;
      }
    }
  }
}

extern "C" void kernel_launch(void* const* d_in, const int* in_sizes, int n_in,
                              void* d_out, int out_size, void* d_ws, size_t ws_size,
                              hipStream_t stream) {
  const float* x      = (const float*)d_in[0];
  const float* rope   = (const float*)d_in[1];
  const float* qkv_w  = (const float*)d_in[2];
  const float* q_bias = (const float*)d_in[3];
  const float* v_bias = (const float*)d_in[4];
  const float* proj_w = (const float*)d_in[5];
  const float* proj_b = (const float*)d_in[6];
  float* out = (float*)d_out;

  char* w0 = (char*)d_ws;
  unsigned short* x_bf  = (unsigned short*)w0;                        // dead after gemm1
  unsigned short* wq_bf = (unsigned short*)(w0 + 50343936);
  unsigned short* qkv   = (unsigned short*)(w0 + 50343936 + 3538944);
  float*          part  = (float*)w0;                                 // aliases x_bf
  unsigned short* McT   = (unsigned short*)(w0 + 25165824 + 1572864); // 9,437,184 B

  const long n4x = (long)M_TOT*768/4;
  const long n4w = (long)K3*768/4;
  cvt_kernel<<<2048, 256, 0, stream>>>(x, x_bf, qkv_w, wq_bf, n4x, n4x + n4w);

  gemm_qkv_rope<<<2313, 512, 0, stream>>>(x_bf, wq_bf, rope, q_bias, v_bias, qkv);

  kv_partial_kernel<<<dim3(CHUNKS, 96), 256, 0, stream>>>(qkv, part);
  mcomb_kernel<<<192, 256, 0, stream>>>(part, proj_w, McT);

  gemm_final<<<792, 512, 0, stream>>>(qkv, McT, proj_b, out);
}